// Round 1
// baseline (507.448 us; speedup 1.0000x reference)
//
#include <hip/hip_runtime.h>
#include <hip/hip_bf16.h>

#define N_NODES 50000
#define N_EDGES 800000
#define IN_DIM 256
#define HEADS 4
#define HEAD_DIM 64
#define OUT_DIM 256
#define NEG_SLOPE 0.2f
#define TOTAL_E (N_EDGES + N_NODES)

// ---------------- GEMM: h = x @ W  (fp32, 64x64 tile, 4x4 microtile) ----------------
__global__ __launch_bounds__(256) void gemm64(const float* __restrict__ A,
                                              const float* __restrict__ B,
                                              float* __restrict__ C, int M) {
    __shared__ float As[16][64 + 4];
    __shared__ float Bs[16][64 + 4];
    const int row0 = blockIdx.x * 64;
    const int col0 = blockIdx.y * 64;
    const int tid = threadIdx.x;
    const int tx = tid & 15, ty = tid >> 4;

    float acc[4][4] = {};

    for (int k0 = 0; k0 < IN_DIM; k0 += 16) {
        // A tile: 64 rows x 16 k. thread loads 4 consecutive floats.
        {
            int r = tid >> 2;              // 0..63
            int kk = (tid & 3) * 4;        // 0,4,8,12
            int gr = row0 + r;
            float4 v = make_float4(0.f, 0.f, 0.f, 0.f);
            if (gr < M) v = *(const float4*)&A[gr * IN_DIM + k0 + kk];
            As[kk + 0][r] = v.x;
            As[kk + 1][r] = v.y;
            As[kk + 2][r] = v.z;
            As[kk + 3][r] = v.w;
        }
        // B tile: 16 k x 64 cols. thread loads 4 consecutive floats.
        {
            int kk = tid >> 4;             // 0..15
            int c = (tid & 15) * 4;        // 0..60
            float4 v = *(const float4*)&B[(k0 + kk) * OUT_DIM + col0 + c];
            Bs[kk][c + 0] = v.x;
            Bs[kk][c + 1] = v.y;
            Bs[kk][c + 2] = v.z;
            Bs[kk][c + 3] = v.w;
        }
        __syncthreads();
#pragma unroll
        for (int kk = 0; kk < 16; ++kk) {
            float ra[4], rb[4];
#pragma unroll
            for (int i = 0; i < 4; ++i) ra[i] = As[kk][ty * 4 + i];
#pragma unroll
            for (int j = 0; j < 4; ++j) rb[j] = Bs[kk][tx * 4 + j];
#pragma unroll
            for (int i = 0; i < 4; ++i)
#pragma unroll
                for (int j = 0; j < 4; ++j) acc[i][j] += ra[i] * rb[j];
        }
        __syncthreads();
    }
#pragma unroll
    for (int i = 0; i < 4; ++i) {
        int gr = row0 + ty * 4 + i;
        if (gr < M) {
            float4 v = make_float4(acc[i][0], acc[i][1], acc[i][2], acc[i][3]);
            *(float4*)&C[gr * OUT_DIM + col0 + tx * 4] = v;
        }
    }
}

// ---------------- per-node attention logits ----------------
__global__ __launch_bounds__(256) void att_kernel(const float* __restrict__ h,
                                                  const float* __restrict__ att_src,
                                                  const float* __restrict__ att_dst,
                                                  float* __restrict__ a_src,
                                                  float* __restrict__ a_dst) {
    int n = blockIdx.x;
    int w = threadIdx.x >> 6;
    int lane = threadIdx.x & 63;
    float v = h[n * OUT_DIM + w * HEAD_DIM + lane];
    float s = v * att_src[w * HEAD_DIM + lane];
    float d = v * att_dst[w * HEAD_DIM + lane];
#pragma unroll
    for (int off = 32; off > 0; off >>= 1) {
        s += __shfl_down(s, off);
        d += __shfl_down(d, off);
    }
    if (lane == 0) {
        a_src[n * HEADS + w] = s;
        a_dst[n * HEADS + w] = d;
    }
}

// ---------------- CSR build ----------------
__global__ void init_deg(int* __restrict__ deg) {
    int i = blockIdx.x * 256 + threadIdx.x;
    if (i < N_NODES) deg[i] = 1;  // self-loop
}

__global__ void hist_kernel(const int* __restrict__ dst, int* __restrict__ deg) {
    int e = blockIdx.x * 256 + threadIdx.x;
    if (e < N_EDGES) atomicAdd(&deg[dst[e]], 1);
}

__global__ __launch_bounds__(256) void scan_phase1(const int* __restrict__ deg,
                                                   int* __restrict__ offs,
                                                   int* __restrict__ bsums) {
    __shared__ int tmp[256];
    int gid = blockIdx.x * 256 + threadIdx.x;
    int v = (gid < N_NODES) ? deg[gid] : 0;
    tmp[threadIdx.x] = v;
    __syncthreads();
    for (int off = 1; off < 256; off <<= 1) {
        int t = (threadIdx.x >= off) ? tmp[threadIdx.x - off] : 0;
        __syncthreads();
        tmp[threadIdx.x] += t;
        __syncthreads();
    }
    if (gid < N_NODES) offs[gid] = tmp[threadIdx.x] - v;  // exclusive
    if (threadIdx.x == 255) bsums[blockIdx.x] = tmp[255];
}

__global__ __launch_bounds__(256) void scan_phase2(const int* __restrict__ bsums,
                                                   int* __restrict__ boffs, int nb) {
    __shared__ int tmp[256];
    int v = (threadIdx.x < nb) ? bsums[threadIdx.x] : 0;
    tmp[threadIdx.x] = v;
    __syncthreads();
    for (int off = 1; off < 256; off <<= 1) {
        int t = (threadIdx.x >= off) ? tmp[threadIdx.x - off] : 0;
        __syncthreads();
        tmp[threadIdx.x] += t;
        __syncthreads();
    }
    boffs[threadIdx.x] = tmp[threadIdx.x] - v;  // exclusive
}

__global__ void scan_phase3(int* __restrict__ offs, const int* __restrict__ boffs,
                            int* __restrict__ cursor) {
    int gid = blockIdx.x * 256 + threadIdx.x;
    if (gid < N_NODES) {
        int o = offs[gid] + boffs[blockIdx.x];
        offs[gid] = o;
        cursor[gid] = o;
    }
    if (gid == 0) offs[N_NODES] = TOTAL_E;
}

__global__ void scatter_kernel(const int* __restrict__ src, const int* __restrict__ dst,
                               int* __restrict__ cursor, int* __restrict__ csr) {
    int id = blockIdx.x * 256 + threadIdx.x;
    if (id < N_EDGES) {
        int s = src[id];
        int dn = dst[id];
        int pos = atomicAdd(&cursor[dn], 1);
        csr[pos] = s;
    } else if (id < TOTAL_E) {
        int nn = id - N_EDGES;
        int pos = atomicAdd(&cursor[nn], 1);
        csr[pos] = nn;
    }
}

// ---------------- aggregate: online segment-softmax + weighted gather-sum ----------------
__global__ __launch_bounds__(256) void aggregate(const float* __restrict__ h,
                                                 const float* __restrict__ a_src,
                                                 const float* __restrict__ a_dst,
                                                 const int* __restrict__ offs,
                                                 const int* __restrict__ csr,
                                                 const float* __restrict__ bias,
                                                 float* __restrict__ out) {
    int n = blockIdx.x;
    int w = threadIdx.x >> 6;
    int lane = threadIdx.x & 63;
    int beg = offs[n], end = offs[n + 1];
    float adst = a_dst[n * HEADS + w];
    float m = -1e30f, den = 0.f, acc = 0.f;
    for (int i = beg; i < end; ++i) {
        int s = csr[i];
        float e = a_src[s * HEADS + w] + adst;
        e = (e > 0.f) ? e : NEG_SLOPE * e;
        float mn = fmaxf(m, e);
        float scale = __expf(m - mn);
        float p = __expf(e - mn);
        den = den * scale + p;
        acc = acc * scale + p * h[s * OUT_DIM + w * HEAD_DIM + lane];
        m = mn;
    }
    out[n * OUT_DIM + w * HEAD_DIM + lane] = acc / den + bias[w * HEAD_DIM + lane];
}

extern "C" void kernel_launch(void* const* d_in, const int* in_sizes, int n_in,
                              void* d_out, int out_size, void* d_ws, size_t ws_size,
                              hipStream_t stream) {
    const float* x = (const float*)d_in[0];
    const int* ei = (const int*)d_in[1];
    const float* W = (const float*)d_in[2];
    const float* att_src = (const float*)d_in[3];
    const float* att_dst = (const float*)d_in[4];
    const float* bias = (const float*)d_in[5];
    float* out = (float*)d_out;

    const int* e_src = ei;
    const int* e_dst = ei + N_EDGES;

    // workspace carve-up
    char* p = (char*)d_ws;
    auto alloc = [&](size_t bytes) {
        void* r = (void*)p;
        p += (bytes + 255) & ~(size_t)255;
        return r;
    };
    float* h     = (float*)alloc((size_t)N_NODES * OUT_DIM * 4);
    float* asrc  = (float*)alloc((size_t)N_NODES * HEADS * 4);
    float* adst  = (float*)alloc((size_t)N_NODES * HEADS * 4);
    int* deg     = (int*)alloc((size_t)N_NODES * 4);
    int* offs    = (int*)alloc((size_t)(N_NODES + 1) * 4);
    int* cursor  = (int*)alloc((size_t)N_NODES * 4);
    int* bsums   = (int*)alloc(256 * 4);
    int* boffs   = (int*)alloc(256 * 4);
    int* csr     = (int*)alloc((size_t)TOTAL_E * 4);

    const int SCAN_BLOCKS = (N_NODES + 255) / 256;  // 196

    gemm64<<<dim3((N_NODES + 63) / 64, OUT_DIM / 64), 256, 0, stream>>>(x, W, h, N_NODES);
    att_kernel<<<N_NODES, 256, 0, stream>>>(h, att_src, att_dst, asrc, adst);
    init_deg<<<SCAN_BLOCKS, 256, 0, stream>>>(deg);
    hist_kernel<<<(N_EDGES + 255) / 256, 256, 0, stream>>>(e_dst, deg);
    scan_phase1<<<SCAN_BLOCKS, 256, 0, stream>>>(deg, offs, bsums);
    scan_phase2<<<1, 256, 0, stream>>>(bsums, boffs, SCAN_BLOCKS);
    scan_phase3<<<SCAN_BLOCKS, 256, 0, stream>>>(offs, boffs, cursor);
    scatter_kernel<<<(TOTAL_E + 255) / 256, 256, 0, stream>>>(e_src, e_dst, cursor, csr);
    aggregate<<<N_NODES, 256, 0, stream>>>(h, asrc, adst, offs, csr, bias, out);
}